// Round 1
// baseline (66.980 us; speedup 1.0000x reference)
//
#include <hip/hip_runtime.h>

// Spatial transformer, bilinear sampling, NCHW fp32.
// X: (B, C, H, W) = (32, 3, 512, 512), theta: (B, 6), out: (B, C, H, W).

#define ST_H 512
#define ST_W 512
#define ST_C 3

__global__ __launch_bounds__(256) void st_bilinear_kernel(
    const float* __restrict__ X,
    const float* __restrict__ theta,
    float* __restrict__ out,
    int B)
{
    const int gid = blockIdx.x * 256 + threadIdx.x;
    const int pix = gid & (ST_H * ST_W - 1);   // 2^18 pixels per image
    const int b   = gid >> 18;
    if (b >= B) return;

    const int h = pix >> 9;      // / 512
    const int w = pix & 511;

    // theta row (broadcast within block via cache; 6 scalar loads)
    const float* t = theta + b * 6;
    const float t00 = t[0], t01 = t[1], t02 = t[2];
    const float t10 = t[3], t11 = t[4], t12 = t[5];

    // linspace(-1, 1, 512) computed like np.linspace (f64 then cast)
    const float xg = (float)(-1.0 + (2.0 / 511.0) * (double)w);
    const float yg = (float)(-1.0 + (2.0 / 511.0) * (double)h);

    // affine transform (same op order as einsum row dot)
    const float x_s = t00 * xg + t01 * yg + t02;
    const float y_s = t10 * xg + t11 * yg + t12;
    const float x = (x_s + 1.0f) * (0.5f * ST_W);
    const float y = (y_s + 1.0f) * (0.5f * ST_H);

    const float fx0 = floorf(x);
    const float fy0 = floorf(y);
    const int x0 = (int)fx0, y0 = (int)fy0;
    const int x1 = x0 + 1,  y1 = y0 + 1;

    const int x0c = min(max(x0, 0), ST_W - 1);
    const int x1c = min(max(x1, 0), ST_W - 1);
    const int y0c = min(max(y0, 0), ST_H - 1);
    const int y1c = min(max(y1, 0), ST_H - 1);

    // weights use CLIPPED coords cast to float (reference semantics)
    const float x0f = (float)x0c, x1f = (float)x1c;
    const float y0f = (float)y0c, y1f = (float)y1c;
    const float wa = (x1f - x) * (y1f - y);
    const float wb = (x1f - x) * (y - y0f);
    const float wc = (x - x0f) * (y1f - y);
    const float wd = (x - x0f) * (y - y0f);

    const int ia = y0c * ST_W + x0c;
    const int ib = y1c * ST_W + x0c;
    const int ic = y0c * ST_W + x1c;
    const int id = y1c * ST_W + x1c;

    const float* __restrict__ Xb = X + (size_t)b * (ST_C * ST_H * ST_W);
    float* __restrict__ ob = out + (size_t)b * (ST_C * ST_H * ST_W) + pix;

#pragma unroll
    for (int c = 0; c < ST_C; ++c) {
        const float* __restrict__ Xc = Xb + c * (ST_H * ST_W);
        const float Ia = Xc[ia];
        const float Ib = Xc[ib];
        const float Ic = Xc[ic];
        const float Id = Xc[id];
        ob[c * (ST_H * ST_W)] = wa * Ia + wb * Ib + wc * Ic + wd * Id;
    }
}

extern "C" void kernel_launch(void* const* d_in, const int* in_sizes, int n_in,
                              void* d_out, int out_size, void* d_ws, size_t ws_size,
                              hipStream_t stream) {
    const float* X     = (const float*)d_in[0];
    const float* theta = (const float*)d_in[1];
    float* out         = (float*)d_out;

    const int B = in_sizes[1] / 6;                  // 32
    const int total = B * ST_H * ST_W;              // threads: 1 per spatial pixel
    const int block = 256;
    const int grid = (total + block - 1) / block;   // 32768

    st_bilinear_kernel<<<grid, block, 0, stream>>>(X, theta, out, B);
}